// Round 16
// baseline (694.944 us; speedup 1.0000x reference)
//
#include <hip/hip_runtime.h>
#include <cstdint>

// ---------------------------------------------------------------------------
// SelfAttention (QK-l2norm variant), MI355X/gfx950.
// R16 = R15 + attention VALU/occupancy cuts: (1) softmax shift folded into
// the QK MFMA C-input (STq init = -Mh; exp2 reads accumulator directly,
// bias path shift-invariant); (2) launch_bounds(256,4) — R15 measured 124
// VGPR <= 128 cap, so 4 blocks/CU is attainable without spill (unlike
// R8/R14 where live state ~240). GEMM1 plain bf16 + fused l2norm; GEMM2
// Markidis split (fp32-accurate).
// ---------------------------------------------------------------------------

typedef __bf16 bfx8 __attribute__((ext_vector_type(8)));
typedef __bf16 bfx4 __attribute__((ext_vector_type(4)));
typedef float  f32x4 __attribute__((ext_vector_type(4)));
typedef float  f32x16 __attribute__((ext_vector_type(16)));

#define NB   4
#define NH   16
#define SEQ  2048
#define CH   1024
#define DD   64
#define MROWS (NB*SEQ)             /* 8192 */
#define BHLD  (NB*NH*SEQ*DD)       /* 8388608 */
#define LOG2E 1.44269504088896340736f

__device__ __forceinline__ void async16(void* lds, const void* g) {
  __builtin_amdgcn_global_load_lds((const __attribute__((address_space(1))) void*)g,
                                   (__attribute__((address_space(3))) void*)lds, 16, 0, 0);
}
__device__ __forceinline__ f32x4 mfma16(bfx8 a, bfx8 b, f32x4 c) {
  return __builtin_amdgcn_mfma_f32_16x16x32_bf16(a, b, c, 0, 0, 0);
}
__device__ __forceinline__ f32x16 mfma32(bfx8 a, bfx8 b, f32x16 c) {
  return __builtin_amdgcn_mfma_f32_32x32x16_bf16(a, b, c, 0, 0, 0);
}

extern "C" __device__ float __ocml_exp2_f32(float);
__device__ __forceinline__ float fexp2(float x) {
#if __has_builtin(__builtin_amdgcn_exp2f)
  return __builtin_amdgcn_exp2f(x);
#else
  return __ocml_exp2_f32(x);
#endif
}

// --------------------------- f32 -> bf16 cast (hi only) ---------------------
__global__ __launch_bounds__(256) void cast_kernel(const float4* __restrict__ src,
                                                   __bf16* __restrict__ dst, int n4) {
  int i = blockIdx.x * 256 + threadIdx.x;
  if (i >= n4) return;
  float4 v = src[i];
  float vv[4] = {v.x, v.y, v.z, v.w};
  bfx4 h;
  #pragma unroll
  for (int j = 0; j < 4; ++j) h[j] = (__bf16)vv[j];
  *(bfx4*)(dst + 4*(size_t)i) = h;
}

// --------------------------- hi/lo split (Markidis) -------------------------
__global__ __launch_bounds__(256) void split_kernel(const float4* __restrict__ src,
                                                    __bf16* __restrict__ hi,
                                                    __bf16* __restrict__ lo, int n4) {
  int i = blockIdx.x * 256 + threadIdx.x;
  if (i >= n4) return;
  float4 v = src[i];
  float vv[4] = {v.x, v.y, v.z, v.w};
  bfx4 h, l;
  #pragma unroll
  for (int j = 0; j < 4; ++j) {
    __bf16 hb = (__bf16)vv[j];
    h[j] = hb;
    l[j] = (__bf16)(vv[j] - (float)hb);
  }
  *(bfx4*)(hi + 4*(size_t)i) = h;
  *(bfx4*)(lo + 4*(size_t)i) = l;
}

// --------------------------- bias nonzero scan ------------------------------
__global__ __launch_bounds__(256) void scan_nz(const uint4* __restrict__ p, int n4,
                                               int* __restrict__ flag) {
  unsigned acc = 0;
  const int stride = gridDim.x * 256;
  for (int i = blockIdx.x * 256 + threadIdx.x; i < n4; i += stride) {
    uint4 u = p[i];
    acc |= (u.x | u.y | u.z | u.w) & 0x7fffffffu;
  }
  if (acc) atomicOr(flag, 1);
}

// ------------------- PLAIN bf16 GEMM 128x128 (qkv projection) ---------------
// R10-verified body. Epilogue: +concat(q_bias,0,v_bias), FUSED l2norm
// (+exp(scale)*LOG2E on q); q/k -> [B,H,L,D] bf16, v -> [B,H,D,L].
__global__ __launch_bounds__(256, 2) void gemmq(
    const __bf16* __restrict__ Ag, const __bf16* __restrict__ Bg,
    const int Ntiles, const int K,
    const float* __restrict__ biasA, const float* __restrict__ biasB,
    const float* __restrict__ scale_mul,
    __bf16* __restrict__ outQ, __bf16* __restrict__ outV)
{
  __shared__ alignas(16) char lds[16384];   // A 8KB | B 8KB
  const int tid = threadIdx.x;
  const int lane = tid & 63, w = tid >> 6;
  const int l15 = lane & 15, l4 = lane >> 4;
  const int nwg = (int)gridDim.x;
  const int wk = (int)(blockIdx.x & 7) * (nwg >> 3) + (int)(blockIdx.x >> 3); // nwg%8==0
  const int mt = wk / Ntiles, nt = wk % Ntiles;
  const int m0 = mt * 128, n0 = nt * 128;
  const int wm = (w >> 1) * 64, wn = (w & 1) * 64;

  const f32x4 zz = {0.f, 0.f, 0.f, 0.f};
  f32x4 acc[4][4];
  #pragma unroll
  for (int a = 0; a < 4; ++a)
    #pragma unroll
    for (int b = 0; b < 4; ++b) acc[a][b] = zz;

  int st_row[2], st_c[2], st_lds[2];
  #pragma unroll
  for (int i = 0; i < 2; ++i) {
    const int s = i*256 + tid;
    st_row[i] = s >> 2;
    st_c[i]   = (s & 3) ^ ((st_row[i] >> 1) & 3);
    st_lds[i] = (i*256 + w*64) * 16;
  }

  for (int k0 = 0; k0 < K; k0 += 32) {
    __syncthreads();
    #pragma unroll
    for (int i = 0; i < 2; ++i) {
      const size_t ga = (size_t)(m0 + st_row[i]) * K + (size_t)(k0 + st_c[i]*8);
      const size_t gb = (size_t)(n0 + st_row[i]) * K + (size_t)(k0 + st_c[i]*8);
      async16(lds +        st_lds[i], Ag + ga);
      async16(lds + 8192 + st_lds[i], Bg + gb);
    }
    __syncthreads();

    bfx8 ah[4], bh[4];
    #pragma unroll
    for (int f = 0; f < 4; ++f) {
      const int ra = wm + f*16 + l15;
      ah[f] = *(const bfx8*)(lds + ra*64 + ((l4 ^ ((ra >> 1) & 3)) * 16));
      const int rb = wn + f*16 + l15;
      bh[f] = *(const bfx8*)(lds + 8192 + rb*64 + ((l4 ^ ((rb >> 1) & 3)) * 16));
    }
    __builtin_amdgcn_s_setprio(1);
    #pragma unroll
    for (int mf = 0; mf < 4; ++mf)
      #pragma unroll
      for (int nf = 0; nf < 4; ++nf)
        acc[mf][nf] = mfma16(ah[mf], bh[nf], acc[mf][nf]);
    __builtin_amdgcn_s_setprio(0);
  }

  // ---- epilogue: bias + fused l2norm + scatter (C/D col=l15, row=4*l4+rg)
  const int gcb = n0 + wn;
  const int which = gcb >> 10;                 // 0 q, 1 k, 2 v
  const int hh = (gcb & (CH-1)) >> 6;
  float smul = 1.f;
  if (which == 0) smul = __expf(fminf(scale_mul[hh], 4.605170185988091f)) * LOG2E;
  #pragma unroll
  for (int mf = 0; mf < 4; ++mf)
    #pragma unroll
    for (int rg = 0; rg < 4; ++rg) {
      #pragma unroll
      for (int nf = 0; nf < 4; ++nf) {
        const int gc = gcb + nf*16 + l15;
        acc[mf][nf][rg] += (which == 0) ? biasA[gc]
                         : ((which == 2) ? biasB[gc - 2*CH] : 0.f);
      }
      const int gr = m0 + wm + mf*16 + 4*l4 + rg;
      const int bb = gr >> 11, ll = gr & (SEQ-1);
      float sc = 1.f;
      if (which < 2) {   // fused l2norm over the 64-col head block (f32)
        float ss = 0.f;
        #pragma unroll
        for (int nf = 0; nf < 4; ++nf) ss += acc[mf][nf][rg] * acc[mf][nf][rg];
        ss += __shfl_xor(ss, 1); ss += __shfl_xor(ss, 2);
        ss += __shfl_xor(ss, 4); ss += __shfl_xor(ss, 8);
        sc = smul / fmaxf(sqrtf(ss), 1e-12f);
      }
      #pragma unroll
      for (int nf = 0; nf < 4; ++nf) {
        const float v = acc[mf][nf][rg] * sc;
        const int dd = nf*16 + l15;
        if (which < 2)
          outQ[(size_t)which*BHLD + ((size_t)((bb*NH + hh)*SEQ) + ll)*DD + dd] = (__bf16)v;
        else
          outV[((size_t)(bb*NH + hh)*DD + dd)*SEQ + ll] = (__bf16)v;
      }
    }
}

// --------------------------- split-bf16 GEMM (output proj) ------------------
__global__ __launch_bounds__(256, 2) void gemm128s(
    const __bf16* __restrict__ Agh, const __bf16* __restrict__ Agl,
    const __bf16* __restrict__ Bgh, const __bf16* __restrict__ Bgl,
    const int Ntiles, const int K,
    const float* __restrict__ biasA, float* __restrict__ outF)
{
  __shared__ alignas(16) char lds[32768];   // Ah | Al | Bh | Bl, 8KB each
  const int tid = threadIdx.x;
  const int lane = tid & 63, w = tid >> 6;
  const int l15 = lane & 15, l4 = lane >> 4;
  const int nwg = (int)gridDim.x;
  const int wk = (int)(blockIdx.x & 7) * (nwg >> 3) + (int)(blockIdx.x >> 3);
  const int mt = wk / Ntiles, nt = wk % Ntiles;
  const int m0 = mt * 128, n0 = nt * 128;
  const int wm = (w >> 1) * 64, wn = (w & 1) * 64;

  const f32x4 zz = {0.f, 0.f, 0.f, 0.f};
  f32x4 acc[4][4];
  #pragma unroll
  for (int a = 0; a < 4; ++a)
    #pragma unroll
    for (int b = 0; b < 4; ++b) acc[a][b] = zz;

  int st_row[2], st_c[2], st_lds[2];
  #pragma unroll
  for (int i = 0; i < 2; ++i) {
    const int s = i*256 + tid;
    st_row[i] = s >> 2;
    st_c[i]   = (s & 3) ^ ((st_row[i] >> 1) & 3);
    st_lds[i] = (i*256 + w*64) * 16;
  }

  for (int k0 = 0; k0 < K; k0 += 32) {
    __syncthreads();
    #pragma unroll
    for (int i = 0; i < 2; ++i) {
      const size_t ga = (size_t)(m0 + st_row[i]) * K + (size_t)(k0 + st_c[i]*8);
      const size_t gb = (size_t)(n0 + st_row[i]) * K + (size_t)(k0 + st_c[i]*8);
      async16(lds +         st_lds[i], Agh + ga);
      async16(lds +  8192 + st_lds[i], Agl + ga);
      async16(lds + 16384 + st_lds[i], Bgh + gb);
      async16(lds + 24576 + st_lds[i], Bgl + gb);
    }
    __syncthreads();

    bfx8 ah[4], al[4], bh[4], bl[4];
    #pragma unroll
    for (int f = 0; f < 4; ++f) {
      const int ra = wm + f*16 + l15;
      const int oa = ra*64 + ((l4 ^ ((ra >> 1) & 3)) * 16);
      ah[f] = *(const bfx8*)(lds + oa);
      al[f] = *(const bfx8*)(lds + 8192 + oa);
      const int rb = wn + f*16 + l15;
      const int ob = rb*64 + ((l4 ^ ((rb >> 1) & 3)) * 16);
      bh[f] = *(const bfx8*)(lds + 16384 + ob);
      bl[f] = *(const bfx8*)(lds + 24576 + ob);
    }
    __builtin_amdgcn_s_setprio(1);
    #pragma unroll
    for (int mf = 0; mf < 4; ++mf)
      #pragma unroll
      for (int nf = 0; nf < 4; ++nf) {
        acc[mf][nf] = mfma16(al[mf], bh[nf], acc[mf][nf]);
        acc[mf][nf] = mfma16(ah[mf], bl[nf], acc[mf][nf]);
        acc[mf][nf] = mfma16(ah[mf], bh[nf], acc[mf][nf]);
      }
    __builtin_amdgcn_s_setprio(0);
  }

  #pragma unroll
  for (int mf = 0; mf < 4; ++mf)
    #pragma unroll
    for (int nf = 0; nf < 4; ++nf)
      #pragma unroll
      for (int rg = 0; rg < 4; ++rg) {
        const int gr = m0 + wm + mf*16 + 4*l4 + rg;
        const int gc = n0 + wn + nf*16 + l15;
        outF[(size_t)gr*CH + gc] = acc[mf][nf][rg] + biasA[gc];
      }
}

// --------- flash attention (bf16, 32x32, reg-P, QBLK=64/wave, sequenced) ----
// Block = 256 q (4 waves x 64 q as 2 q-blocks of 32). KVBLK=64, dbuf Ks/Vt
// (2x8KB each) = 32KB, no P LDS. STq C-init = -Mh (softmax shift free via
// MFMA C-input; bias path shift-invariant). launch_bounds(256,4): R15
// measured 124 VGPR -> 4 blocks/CU attainable. l per-lane partial.
__global__ __launch_bounds__(256, 4) void attn_kernel(
    const __bf16* __restrict__ qn, const __bf16* __restrict__ kn,
    const __bf16* __restrict__ vtg, const float* __restrict__ scale_mul,
    const float* __restrict__ bias, const int* __restrict__ flag,
    __bf16* __restrict__ ao_hi, __bf16* __restrict__ ao_lo)
{
  __shared__ alignas(16) char Ks[2][8192];
  __shared__ alignas(16) char Vt[2][8192];

  const int tid = threadIdx.x, lane = tid & 63, w = tid >> 6;
  const int l31 = lane & 31, l5 = lane >> 5;
  const int wk = (int)(blockIdx.x & 7) * 64 + (int)(blockIdx.x >> 3);  // grid 512
  const int qt = wk & 7, h = (wk >> 3) & 15, b = wk >> 7;
  const size_t bh = ((size_t)(b*NH + h)) * SEQ * DD;
  const int hasbias = *flag;

  // per-head provable score bound in log2 units (q scaled by sm*LOG2E, |cos|<=1)
  const float Mh = __expf(fminf(scale_mul[h], 4.605170185988091f)) * LOG2E * 1.01f;

  // Q fragments (B-operand: col=q=lane&31, k(d) = 16*kd + 8*l5 + j), 2 q-blocks
  bfx8 Qf[2][4];
  const int q0 = qt*256 + w*64;
  #pragma unroll
  for (int qb = 0; qb < 2; ++qb)
    #pragma unroll
    for (int kd = 0; kd < 4; ++kd)
      Qf[qb][kd] = *(const bfx8*)(qn + bh + (size_t)(q0 + qb*32 + l31)*DD + kd*16 + l5*8);

  f32x16 O[2][2];
  #pragma unroll
  for (int qb = 0; qb < 2; ++qb)
    #pragma unroll
    for (int r = 0; r < 16; ++r) { O[qb][0][r] = 0.f; O[qb][1][r] = 0.f; }
  float m_[2] = {0.f, 0.f}, l_[2] = {0.f, 0.f};   // m_ in SHIFTED units (s-Mh)

  auto stage = [&](int t, int buf) {
    const __bf16* ksrc = kn + bh + (size_t)t*64*DD;
    const __bf16* vsrc = vtg + bh + (size_t)t*64;
    #pragma unroll
    for (int i = 0; i < 2; ++i) {
      const int s = i*256 + tid;
      const int row = s >> 3;
      const int c = (s & 7) ^ (row & 7);
      async16(Ks[buf] + (size_t)(i*256 + w*64)*16, ksrc + (size_t)row*DD + c*8);
      async16(Vt[buf] + (size_t)(i*256 + w*64)*16, vsrc + (size_t)row*SEQ + c*8);
    }
  };

  if (hasbias) { m_[0] = -1e30f; m_[1] = -1e30f; }

  stage(0, 0);
  asm volatile("s_waitcnt vmcnt(0)" ::: "memory");
  __builtin_amdgcn_s_barrier();

  #pragma unroll 1
  for (int t = 0; t < 32; ++t) {
    const int cur = t & 1;
    if (t + 1 < 32) stage(t + 1, cur ^ 1);   // overlaps tile-t compute

    bfx8 Pf[2][4];       // both q-blocks' P fragments (32 VGPR), fed to PV

    #pragma unroll
    for (int qb = 0; qb < 2; ++qb) {
      // ---- S^T - Mh = K Q^T + C(-Mh)  (shift folded into MFMA C-input) ----
      f32x16 STq[2];
      #pragma unroll
      for (int kb = 0; kb < 2; ++kb)
        #pragma unroll
        for (int r = 0; r < 16; ++r) STq[kb][r] = -Mh;
      __builtin_amdgcn_s_setprio(1);
      #pragma unroll
      for (int kb = 0; kb < 2; ++kb)
        #pragma unroll
        for (int kd = 0; kd < 4; ++kd) {
          const int row = kb*32 + l31;
          const int c = (2*kd + l5) ^ (l31 & 7);
          const bfx8 Kf = *(const bfx8*)(Ks[cur] + row*128 + c*16);
          STq[kb] = mfma32(Kf, Qf[qb][kd], STq[kb]);
        }
      __builtin_amdgcn_s_setprio(0);

      // ---- softmax -> bf16 groups (k base = 32kb+8rh+4l5, 4 wide) ----
      unsigned g32[2][4][2];
      if (!hasbias) {
        float ls = 0.f;
        #pragma unroll
        for (int kb = 0; kb < 2; ++kb)
          #pragma unroll
          for (int rh = 0; rh < 4; ++rh) {
            bfx4 g;
            #pragma unroll
            for (int j = 0; j < 4; ++j) {
              const float e = fexp2(STq[kb][4*rh + j]);   // shift pre-applied
              ls += e;
              g[j] = (__bf16)e;
            }
            union { bfx4 b; unsigned u[2]; } cv; cv.b = g;
            g32[kb][rh][0] = cv.u[0];
            g32[kb][rh][1] = cv.u[1];
          }
        l_[qb] += ls;                     // per-lane partial (k-subset)
      } else {
        // shifted scores; online-max softmax is shift-invariant
        const float* bp = bias + (size_t)(q0 + qb*32 + l31)*SEQ + (size_t)t*64;
        float mx = -1e30f;
        #pragma unroll
        for (int kb = 0; kb < 2; ++kb)
          #pragma unroll
          for (int r = 0; r < 16; ++r) {
            STq[kb][r] += bp[32*kb + 4*l5 + (r & 3) + 8*(r >> 2)] * LOG2E;
            mx = fmaxf(mx, STq[kb][r]);
          }
        mx = fmaxf(mx, __shfl_xor(mx, 32));
        const bool skip = __all(mx - m_[qb] <= 12.0f) != 0;
        const float mn = skip ? m_[qb] : fmaxf(m_[qb], mx);
        float rs = 0.f;
        #pragma unroll
        for (int kb = 0; kb < 2; ++kb)
          #pragma unroll
          for (int r = 0; r < 16; ++r) {
            const float pv = fexp2(STq[kb][r] - mn);
            STq[kb][r] = pv;
            rs += pv;
          }
        if (skip) {
          l_[qb] += rs;                   // per-lane partial
        } else {
          const float corr = fexp2(m_[qb] - mn);
          l_[qb] = l_[qb] * corr + rs;
          m_[qb] = mn;
          #pragma unroll
          for (int db = 0; db < 2; ++db)
            #pragma unroll
            for (int r = 0; r < 16; ++r) O[qb][db][r] *= corr;
        }
        #pragma unroll
        for (int kb = 0; kb < 2; ++kb)
          #pragma unroll
          for (int rh = 0; rh < 4; ++rh) {
            bfx4 g;
            #pragma unroll
            for (int j = 0; j < 4; ++j) g[j] = (__bf16)STq[kb][4*rh + j];
            union { bfx4 b; unsigned u[2]; } cv; cv.b = g;
            g32[kb][rh][0] = cv.u[0];
            g32[kb][rh][1] = cv.u[1];
          }
      }

      // ---- build PV B-fragments via permlane32_swap (k = 16kk+8l5+j) ----
      // v_permlane32_swap_b32 vdst, vsrc : vdst[32:63] <-> vsrc[0:31].
      // vdst=g[e], vsrc=g[e+1]: u' = [g_e.lo|g_e1.lo] (j0-3), v' = [g_e.hi|g_e1.hi]
      #pragma unroll
      for (int kk = 0; kk < 4; ++kk) {
        const int kb = kk >> 1, e = (kk & 1) * 2;
        unsigned u0 = g32[kb][e][0],   u1 = g32[kb][e][1];
        unsigned v0 = g32[kb][e+1][0], v1 = g32[kb][e+1][1];
        asm volatile("v_permlane32_swap_b32 %0, %1" : "+v"(u0), "+v"(v0));
        asm volatile("v_permlane32_swap_b32 %0, %1" : "+v"(u1), "+v"(v1));
        union { unsigned u[4]; bfx8 bv; } fb;
        fb.u[0] = u0; fb.u[1] = u1; fb.u[2] = v0; fb.u[3] = v1;
        Pf[qb][kk] = fb.bv;
      }
    }

    // ---- O^T += V^T P : each Vf read ONCE feeds both q-blocks ----
    __builtin_amdgcn_s_setprio(1);
    #pragma unroll
    for (int kk = 0; kk < 4; ++kk)
      #pragma unroll
      for (int db = 0; db < 2; ++db) {
        const int row = db*32 + l31;
        const int c = (2*kk + l5) ^ (l31 & 7);
        const bfx8 Vf = *(const bfx8*)(Vt[cur] + row*128 + c*16);
        O[0][db] = mfma32(Vf, Pf[0][kk], O[0][db]);
        O[1][db] = mfma32(Vf, Pf[1][kk], O[1][db]);
      }
    __builtin_amdgcn_s_setprio(0);

    asm volatile("s_waitcnt vmcnt(0)" ::: "memory");   // stage(t+1) landed
    __builtin_amdgcn_s_barrier();                      // all waves done with buf cur
  }

  // ---- epilogue: finalize l (lane pair), O/l, hi/lo bf16 split ----
  #pragma unroll
  for (int qb = 0; qb < 2; ++qb) {
    const float lfull = l_[qb] + __shfl_xor(l_[qb], 32);
    const float inv = 1.f / lfull;
    const int qg = q0 + qb*32 + l31;
    #pragma unroll
    for (int db = 0; db < 2; ++db)
      #pragma unroll
      for (int rq = 0; rq < 4; ++rq) {
        bfx4 hb, lb;
        #pragma unroll
        for (int j = 0; j < 4; ++j) {
          const float v = O[qb][db][4*rq + j] * inv;
          hb[j] = (__bf16)v;
          lb[j] = (__bf16)(v - (float)hb[j]);
        }
        const size_t idx = ((size_t)(b*SEQ + qg))*CH + h*DD + db*32 + rq*8 + l5*4;
        *(bfx4*)(ao_hi + idx) = hb;
        *(bfx4*)(ao_lo + idx) = lb;
      }
  }
}

// ---------------------------------------------------------------------------
extern "C" void kernel_launch(void* const* d_in, const int* in_sizes, int n_in,
                              void* d_out, int out_size, void* d_ws, size_t ws_size,
                              hipStream_t stream) {
  const float* x         = (const float*)d_in[0];
  const float* attn_bias = (const float*)d_in[1];
  const float* qkv_w     = (const float*)d_in[2];
  const float* q_bias    = (const float*)d_in[3];
  const float* v_bias    = (const float*)d_in[4];
  const float* scale_mul = (const float*)d_in[5];
  const float* proj_w    = (const float*)d_in[6];
  const float* proj_b    = (const float*)d_in[7];
  float* out = (float*)d_out;

  char* ws = (char*)d_ws;
  size_t off = 0;
  auto alloc = [&](size_t n) { char* p = ws + off; off += (n + 255) & ~(size_t)255; return p; };
  __bf16* x_h  = (__bf16*)alloc((size_t)MROWS*CH*2);
  __bf16* w_h  = (__bf16*)alloc((size_t)3*CH*CH*2);
  __bf16* p_h  = (__bf16*)alloc((size_t)CH*CH*2);
  __bf16* p_l  = (__bf16*)alloc((size_t)CH*CH*2);
  __bf16* qkvn = (__bf16*)alloc((size_t)2*BHLD*2);   // q,k [B,H,L,D] (normalized)
  __bf16* vt   = (__bf16*)alloc((size_t)BHLD*2);     // v   [B,H,D,L]
  __bf16* ao_h = (__bf16*)alloc((size_t)MROWS*CH*2);
  __bf16* ao_l = (__bf16*)alloc((size_t)MROWS*CH*2);
  int*    flag = (int*)alloc(256);

  cast_kernel<<<MROWS*CH/4/256, 256, 0, stream>>>((const float4*)x, x_h, MROWS*CH/4);
  cast_kernel<<<3*CH*CH/4/256, 256, 0, stream>>>((const float4*)qkv_w, w_h, 3*CH*CH/4);
  split_kernel<<<CH*CH/4/256, 256, 0, stream>>>((const float4*)proj_w, p_h, p_l, CH*CH/4);

  hipMemsetAsync(flag, 0, sizeof(int), stream);
  scan_nz<<<2048, 256, 0, stream>>>((const uint4*)attn_bias, SEQ*SEQ/4, flag);

  // GEMM1 (plain bf16): [8192,3072] = x*qkv_w^T (+bias, +fused l2norm)
  gemmq<<<(MROWS/128)*(3*CH/128), 256, 0, stream>>>(
      x_h, w_h, 3*CH/128, CH, q_bias, v_bias, scale_mul, qkvn, vt);

  attn_kernel<<<NB*NH*(SEQ/256), 256, 0, stream>>>(
      qkvn, qkvn + (size_t)BHLD, vt, scale_mul, attn_bias, flag, ao_h, ao_l);

  // GEMM2 (split, fp32-accurate): d_out = attn_out * proj_w^T + proj_b
  gemm128s<<<(MROWS/128)*(CH/128), 256, 0, stream>>>(
      ao_h, ao_l, p_h, p_l, CH/128, CH, proj_b, out);
}

// Round 17
// 266.660 us; speedup vs baseline: 2.6061x; 2.6061x over previous
//
#include <hip/hip_runtime.h>
#include <cstdint>

// ---------------------------------------------------------------------------
// SelfAttention (QK-l2norm variant), MI355X/gfx950.
// R17 = R15 (verified 267us) + softmax shift folded into QK MFMA C-input
// (STq init = -Mh), at launch_bounds(256,2). R16 lesson (3rd occurrence):
// NEVER request >2 waves/SIMD — (256,4) collapses regalloc to 64 VGPR and
// spills GB of scratch. Attn occupancy is grid-limited (512 blocks = 2/CU),
// not register-limited. GEMM1 plain bf16 + fused l2norm; GEMM2 Markidis
// hi/lo split (fp32-accurate).
// ---------------------------------------------------------------------------

typedef __bf16 bfx8 __attribute__((ext_vector_type(8)));
typedef __bf16 bfx4 __attribute__((ext_vector_type(4)));
typedef float  f32x4 __attribute__((ext_vector_type(4)));
typedef float  f32x16 __attribute__((ext_vector_type(16)));

#define NB   4
#define NH   16
#define SEQ  2048
#define CH   1024
#define DD   64
#define MROWS (NB*SEQ)             /* 8192 */
#define BHLD  (NB*NH*SEQ*DD)       /* 8388608 */
#define LOG2E 1.44269504088896340736f

__device__ __forceinline__ void async16(void* lds, const void* g) {
  __builtin_amdgcn_global_load_lds((const __attribute__((address_space(1))) void*)g,
                                   (__attribute__((address_space(3))) void*)lds, 16, 0, 0);
}
__device__ __forceinline__ f32x4 mfma16(bfx8 a, bfx8 b, f32x4 c) {
  return __builtin_amdgcn_mfma_f32_16x16x32_bf16(a, b, c, 0, 0, 0);
}
__device__ __forceinline__ f32x16 mfma32(bfx8 a, bfx8 b, f32x16 c) {
  return __builtin_amdgcn_mfma_f32_32x32x16_bf16(a, b, c, 0, 0, 0);
}

extern "C" __device__ float __ocml_exp2_f32(float);
__device__ __forceinline__ float fexp2(float x) {
#if __has_builtin(__builtin_amdgcn_exp2f)
  return __builtin_amdgcn_exp2f(x);
#else
  return __ocml_exp2_f32(x);
#endif
}

// --------------------------- f32 -> bf16 cast (hi only) ---------------------
__global__ __launch_bounds__(256) void cast_kernel(const float4* __restrict__ src,
                                                   __bf16* __restrict__ dst, int n4) {
  int i = blockIdx.x * 256 + threadIdx.x;
  if (i >= n4) return;
  float4 v = src[i];
  float vv[4] = {v.x, v.y, v.z, v.w};
  bfx4 h;
  #pragma unroll
  for (int j = 0; j < 4; ++j) h[j] = (__bf16)vv[j];
  *(bfx4*)(dst + 4*(size_t)i) = h;
}

// --------------------------- hi/lo split (Markidis) -------------------------
__global__ __launch_bounds__(256) void split_kernel(const float4* __restrict__ src,
                                                    __bf16* __restrict__ hi,
                                                    __bf16* __restrict__ lo, int n4) {
  int i = blockIdx.x * 256 + threadIdx.x;
  if (i >= n4) return;
  float4 v = src[i];
  float vv[4] = {v.x, v.y, v.z, v.w};
  bfx4 h, l;
  #pragma unroll
  for (int j = 0; j < 4; ++j) {
    __bf16 hb = (__bf16)vv[j];
    h[j] = hb;
    l[j] = (__bf16)(vv[j] - (float)hb);
  }
  *(bfx4*)(hi + 4*(size_t)i) = h;
  *(bfx4*)(lo + 4*(size_t)i) = l;
}

// --------------------------- bias nonzero scan ------------------------------
__global__ __launch_bounds__(256) void scan_nz(const uint4* __restrict__ p, int n4,
                                               int* __restrict__ flag) {
  unsigned acc = 0;
  const int stride = gridDim.x * 256;
  for (int i = blockIdx.x * 256 + threadIdx.x; i < n4; i += stride) {
    uint4 u = p[i];
    acc |= (u.x | u.y | u.z | u.w) & 0x7fffffffu;
  }
  if (acc) atomicOr(flag, 1);
}

// ------------------- PLAIN bf16 GEMM 128x128 (qkv projection) ---------------
// R10-verified body. Epilogue: +concat(q_bias,0,v_bias), FUSED l2norm
// (+exp(scale)*LOG2E on q); q/k -> [B,H,L,D] bf16, v -> [B,H,D,L].
__global__ __launch_bounds__(256, 2) void gemmq(
    const __bf16* __restrict__ Ag, const __bf16* __restrict__ Bg,
    const int Ntiles, const int K,
    const float* __restrict__ biasA, const float* __restrict__ biasB,
    const float* __restrict__ scale_mul,
    __bf16* __restrict__ outQ, __bf16* __restrict__ outV)
{
  __shared__ alignas(16) char lds[16384];   // A 8KB | B 8KB
  const int tid = threadIdx.x;
  const int lane = tid & 63, w = tid >> 6;
  const int l15 = lane & 15, l4 = lane >> 4;
  const int nwg = (int)gridDim.x;
  const int wk = (int)(blockIdx.x & 7) * (nwg >> 3) + (int)(blockIdx.x >> 3); // nwg%8==0
  const int mt = wk / Ntiles, nt = wk % Ntiles;
  const int m0 = mt * 128, n0 = nt * 128;
  const int wm = (w >> 1) * 64, wn = (w & 1) * 64;

  const f32x4 zz = {0.f, 0.f, 0.f, 0.f};
  f32x4 acc[4][4];
  #pragma unroll
  for (int a = 0; a < 4; ++a)
    #pragma unroll
    for (int b = 0; b < 4; ++b) acc[a][b] = zz;

  int st_row[2], st_c[2], st_lds[2];
  #pragma unroll
  for (int i = 0; i < 2; ++i) {
    const int s = i*256 + tid;
    st_row[i] = s >> 2;
    st_c[i]   = (s & 3) ^ ((st_row[i] >> 1) & 3);
    st_lds[i] = (i*256 + w*64) * 16;
  }

  for (int k0 = 0; k0 < K; k0 += 32) {
    __syncthreads();
    #pragma unroll
    for (int i = 0; i < 2; ++i) {
      const size_t ga = (size_t)(m0 + st_row[i]) * K + (size_t)(k0 + st_c[i]*8);
      const size_t gb = (size_t)(n0 + st_row[i]) * K + (size_t)(k0 + st_c[i]*8);
      async16(lds +        st_lds[i], Ag + ga);
      async16(lds + 8192 + st_lds[i], Bg + gb);
    }
    __syncthreads();

    bfx8 ah[4], bh[4];
    #pragma unroll
    for (int f = 0; f < 4; ++f) {
      const int ra = wm + f*16 + l15;
      ah[f] = *(const bfx8*)(lds + ra*64 + ((l4 ^ ((ra >> 1) & 3)) * 16));
      const int rb = wn + f*16 + l15;
      bh[f] = *(const bfx8*)(lds + 8192 + rb*64 + ((l4 ^ ((rb >> 1) & 3)) * 16));
    }
    __builtin_amdgcn_s_setprio(1);
    #pragma unroll
    for (int mf = 0; mf < 4; ++mf)
      #pragma unroll
      for (int nf = 0; nf < 4; ++nf)
        acc[mf][nf] = mfma16(ah[mf], bh[nf], acc[mf][nf]);
    __builtin_amdgcn_s_setprio(0);
  }

  // ---- epilogue: bias + fused l2norm + scatter (C/D col=l15, row=4*l4+rg)
  const int gcb = n0 + wn;
  const int which = gcb >> 10;                 // 0 q, 1 k, 2 v
  const int hh = (gcb & (CH-1)) >> 6;
  float smul = 1.f;
  if (which == 0) smul = __expf(fminf(scale_mul[hh], 4.605170185988091f)) * LOG2E;
  #pragma unroll
  for (int mf = 0; mf < 4; ++mf)
    #pragma unroll
    for (int rg = 0; rg < 4; ++rg) {
      #pragma unroll
      for (int nf = 0; nf < 4; ++nf) {
        const int gc = gcb + nf*16 + l15;
        acc[mf][nf][rg] += (which == 0) ? biasA[gc]
                         : ((which == 2) ? biasB[gc - 2*CH] : 0.f);
      }
      const int gr = m0 + wm + mf*16 + 4*l4 + rg;
      const int bb = gr >> 11, ll = gr & (SEQ-1);
      float sc = 1.f;
      if (which < 2) {   // fused l2norm over the 64-col head block (f32)
        float ss = 0.f;
        #pragma unroll
        for (int nf = 0; nf < 4; ++nf) ss += acc[mf][nf][rg] * acc[mf][nf][rg];
        ss += __shfl_xor(ss, 1); ss += __shfl_xor(ss, 2);
        ss += __shfl_xor(ss, 4); ss += __shfl_xor(ss, 8);
        sc = smul / fmaxf(sqrtf(ss), 1e-12f);
      }
      #pragma unroll
      for (int nf = 0; nf < 4; ++nf) {
        const float v = acc[mf][nf][rg] * sc;
        const int dd = nf*16 + l15;
        if (which < 2)
          outQ[(size_t)which*BHLD + ((size_t)((bb*NH + hh)*SEQ) + ll)*DD + dd] = (__bf16)v;
        else
          outV[((size_t)(bb*NH + hh)*DD + dd)*SEQ + ll] = (__bf16)v;
      }
    }
}

// --------------------------- split-bf16 GEMM (output proj) ------------------
__global__ __launch_bounds__(256, 2) void gemm128s(
    const __bf16* __restrict__ Agh, const __bf16* __restrict__ Agl,
    const __bf16* __restrict__ Bgh, const __bf16* __restrict__ Bgl,
    const int Ntiles, const int K,
    const float* __restrict__ biasA, float* __restrict__ outF)
{
  __shared__ alignas(16) char lds[32768];   // Ah | Al | Bh | Bl, 8KB each
  const int tid = threadIdx.x;
  const int lane = tid & 63, w = tid >> 6;
  const int l15 = lane & 15, l4 = lane >> 4;
  const int nwg = (int)gridDim.x;
  const int wk = (int)(blockIdx.x & 7) * (nwg >> 3) + (int)(blockIdx.x >> 3);
  const int mt = wk / Ntiles, nt = wk % Ntiles;
  const int m0 = mt * 128, n0 = nt * 128;
  const int wm = (w >> 1) * 64, wn = (w & 1) * 64;

  const f32x4 zz = {0.f, 0.f, 0.f, 0.f};
  f32x4 acc[4][4];
  #pragma unroll
  for (int a = 0; a < 4; ++a)
    #pragma unroll
    for (int b = 0; b < 4; ++b) acc[a][b] = zz;

  int st_row[2], st_c[2], st_lds[2];
  #pragma unroll
  for (int i = 0; i < 2; ++i) {
    const int s = i*256 + tid;
    st_row[i] = s >> 2;
    st_c[i]   = (s & 3) ^ ((st_row[i] >> 1) & 3);
    st_lds[i] = (i*256 + w*64) * 16;
  }

  for (int k0 = 0; k0 < K; k0 += 32) {
    __syncthreads();
    #pragma unroll
    for (int i = 0; i < 2; ++i) {
      const size_t ga = (size_t)(m0 + st_row[i]) * K + (size_t)(k0 + st_c[i]*8);
      const size_t gb = (size_t)(n0 + st_row[i]) * K + (size_t)(k0 + st_c[i]*8);
      async16(lds +         st_lds[i], Agh + ga);
      async16(lds +  8192 + st_lds[i], Agl + ga);
      async16(lds + 16384 + st_lds[i], Bgh + gb);
      async16(lds + 24576 + st_lds[i], Bgl + gb);
    }
    __syncthreads();

    bfx8 ah[4], al[4], bh[4], bl[4];
    #pragma unroll
    for (int f = 0; f < 4; ++f) {
      const int ra = wm + f*16 + l15;
      const int oa = ra*64 + ((l4 ^ ((ra >> 1) & 3)) * 16);
      ah[f] = *(const bfx8*)(lds + oa);
      al[f] = *(const bfx8*)(lds + 8192 + oa);
      const int rb = wn + f*16 + l15;
      const int ob = rb*64 + ((l4 ^ ((rb >> 1) & 3)) * 16);
      bh[f] = *(const bfx8*)(lds + 16384 + ob);
      bl[f] = *(const bfx8*)(lds + 24576 + ob);
    }
    __builtin_amdgcn_s_setprio(1);
    #pragma unroll
    for (int mf = 0; mf < 4; ++mf)
      #pragma unroll
      for (int nf = 0; nf < 4; ++nf) {
        acc[mf][nf] = mfma16(al[mf], bh[nf], acc[mf][nf]);
        acc[mf][nf] = mfma16(ah[mf], bl[nf], acc[mf][nf]);
        acc[mf][nf] = mfma16(ah[mf], bh[nf], acc[mf][nf]);
      }
    __builtin_amdgcn_s_setprio(0);
  }

  #pragma unroll
  for (int mf = 0; mf < 4; ++mf)
    #pragma unroll
    for (int nf = 0; nf < 4; ++nf)
      #pragma unroll
      for (int rg = 0; rg < 4; ++rg) {
        const int gr = m0 + wm + mf*16 + 4*l4 + rg;
        const int gc = n0 + wn + nf*16 + l15;
        outF[(size_t)gr*CH + gc] = acc[mf][nf][rg] + biasA[gc];
      }
}

// --------- flash attention (bf16, 32x32, reg-P, QBLK=64/wave, sequenced) ----
// Block = 256 q (4 waves x 64 q as 2 q-blocks of 32). KVBLK=64, dbuf Ks/Vt
// (2x8KB each) = 32KB, no P LDS. STq C-init = -Mh (softmax shift free via
// MFMA C-input; bias path shift-invariant). launch_bounds(256,2) — R16
// proved (256,4) fatal. l per-lane partial (shfl_xor(32) at end).
__global__ __launch_bounds__(256, 2) void attn_kernel(
    const __bf16* __restrict__ qn, const __bf16* __restrict__ kn,
    const __bf16* __restrict__ vtg, const float* __restrict__ scale_mul,
    const float* __restrict__ bias, const int* __restrict__ flag,
    __bf16* __restrict__ ao_hi, __bf16* __restrict__ ao_lo)
{
  __shared__ alignas(16) char Ks[2][8192];
  __shared__ alignas(16) char Vt[2][8192];

  const int tid = threadIdx.x, lane = tid & 63, w = tid >> 6;
  const int l31 = lane & 31, l5 = lane >> 5;
  const int wk = (int)(blockIdx.x & 7) * 64 + (int)(blockIdx.x >> 3);  // grid 512
  const int qt = wk & 7, h = (wk >> 3) & 15, b = wk >> 7;
  const size_t bh = ((size_t)(b*NH + h)) * SEQ * DD;
  const int hasbias = *flag;

  // per-head provable score bound in log2 units (q scaled by sm*LOG2E, |cos|<=1)
  const float Mh = __expf(fminf(scale_mul[h], 4.605170185988091f)) * LOG2E * 1.01f;

  // Q fragments (B-operand: col=q=lane&31, k(d) = 16*kd + 8*l5 + j), 2 q-blocks
  bfx8 Qf[2][4];
  const int q0 = qt*256 + w*64;
  #pragma unroll
  for (int qb = 0; qb < 2; ++qb)
    #pragma unroll
    for (int kd = 0; kd < 4; ++kd)
      Qf[qb][kd] = *(const bfx8*)(qn + bh + (size_t)(q0 + qb*32 + l31)*DD + kd*16 + l5*8);

  f32x16 O[2][2];
  #pragma unroll
  for (int qb = 0; qb < 2; ++qb)
    #pragma unroll
    for (int r = 0; r < 16; ++r) { O[qb][0][r] = 0.f; O[qb][1][r] = 0.f; }
  float m_[2] = {0.f, 0.f}, l_[2] = {0.f, 0.f};   // m_ in SHIFTED units (s-Mh)

  auto stage = [&](int t, int buf) {
    const __bf16* ksrc = kn + bh + (size_t)t*64*DD;
    const __bf16* vsrc = vtg + bh + (size_t)t*64;
    #pragma unroll
    for (int i = 0; i < 2; ++i) {
      const int s = i*256 + tid;
      const int row = s >> 3;
      const int c = (s & 7) ^ (row & 7);
      async16(Ks[buf] + (size_t)(i*256 + w*64)*16, ksrc + (size_t)row*DD + c*8);
      async16(Vt[buf] + (size_t)(i*256 + w*64)*16, vsrc + (size_t)row*SEQ + c*8);
    }
  };

  if (hasbias) { m_[0] = -1e30f; m_[1] = -1e30f; }

  stage(0, 0);
  asm volatile("s_waitcnt vmcnt(0)" ::: "memory");
  __builtin_amdgcn_s_barrier();

  #pragma unroll 1
  for (int t = 0; t < 32; ++t) {
    const int cur = t & 1;
    if (t + 1 < 32) stage(t + 1, cur ^ 1);   // overlaps tile-t compute

    bfx8 Pf[2][4];       // both q-blocks' P fragments (32 VGPR), fed to PV

    #pragma unroll
    for (int qb = 0; qb < 2; ++qb) {
      // ---- S^T - Mh = K Q^T + C(-Mh)  (shift folded into MFMA C-input) ----
      f32x16 STq[2];
      #pragma unroll
      for (int kb = 0; kb < 2; ++kb)
        #pragma unroll
        for (int r = 0; r < 16; ++r) STq[kb][r] = -Mh;
      __builtin_amdgcn_s_setprio(1);
      #pragma unroll
      for (int kb = 0; kb < 2; ++kb)
        #pragma unroll
        for (int kd = 0; kd < 4; ++kd) {
          const int row = kb*32 + l31;
          const int c = (2*kd + l5) ^ (l31 & 7);
          const bfx8 Kf = *(const bfx8*)(Ks[cur] + row*128 + c*16);
          STq[kb] = mfma32(Kf, Qf[qb][kd], STq[kb]);
        }
      __builtin_amdgcn_s_setprio(0);

      // ---- softmax -> bf16 groups (k base = 32kb+8rh+4l5, 4 wide) ----
      unsigned g32[2][4][2];
      if (!hasbias) {
        float ls = 0.f;
        #pragma unroll
        for (int kb = 0; kb < 2; ++kb)
          #pragma unroll
          for (int rh = 0; rh < 4; ++rh) {
            bfx4 g;
            #pragma unroll
            for (int j = 0; j < 4; ++j) {
              const float e = fexp2(STq[kb][4*rh + j]);   // shift pre-applied
              ls += e;
              g[j] = (__bf16)e;
            }
            union { bfx4 b; unsigned u[2]; } cv; cv.b = g;
            g32[kb][rh][0] = cv.u[0];
            g32[kb][rh][1] = cv.u[1];
          }
        l_[qb] += ls;                     // per-lane partial (k-subset)
      } else {
        // shifted scores; online-max softmax is shift-invariant
        const float* bp = bias + (size_t)(q0 + qb*32 + l31)*SEQ + (size_t)t*64;
        float mx = -1e30f;
        #pragma unroll
        for (int kb = 0; kb < 2; ++kb)
          #pragma unroll
          for (int r = 0; r < 16; ++r) {
            STq[kb][r] += bp[32*kb + 4*l5 + (r & 3) + 8*(r >> 2)] * LOG2E;
            mx = fmaxf(mx, STq[kb][r]);
          }
        mx = fmaxf(mx, __shfl_xor(mx, 32));
        const bool skip = __all(mx - m_[qb] <= 12.0f) != 0;
        const float mn = skip ? m_[qb] : fmaxf(m_[qb], mx);
        float rs = 0.f;
        #pragma unroll
        for (int kb = 0; kb < 2; ++kb)
          #pragma unroll
          for (int r = 0; r < 16; ++r) {
            const float pv = fexp2(STq[kb][r] - mn);
            STq[kb][r] = pv;
            rs += pv;
          }
        if (skip) {
          l_[qb] += rs;                   // per-lane partial
        } else {
          const float corr = fexp2(m_[qb] - mn);
          l_[qb] = l_[qb] * corr + rs;
          m_[qb] = mn;
          #pragma unroll
          for (int db = 0; db < 2; ++db)
            #pragma unroll
            for (int r = 0; r < 16; ++r) O[qb][db][r] *= corr;
        }
        #pragma unroll
        for (int kb = 0; kb < 2; ++kb)
          #pragma unroll
          for (int rh = 0; rh < 4; ++rh) {
            bfx4 g;
            #pragma unroll
            for (int j = 0; j < 4; ++j) g[j] = (__bf16)STq[kb][4*rh + j];
            union { bfx4 b; unsigned u[2]; } cv; cv.b = g;
            g32[kb][rh][0] = cv.u[0];
            g32[kb][rh][1] = cv.u[1];
          }
      }

      // ---- build PV B-fragments via permlane32_swap (k = 16kk+8l5+j) ----
      // v_permlane32_swap_b32 vdst, vsrc : vdst[32:63] <-> vsrc[0:31].
      // vdst=g[e], vsrc=g[e+1]: u' = [g_e.lo|g_e1.lo] (j0-3), v' = [g_e.hi|g_e1.hi]
      #pragma unroll
      for (int kk = 0; kk < 4; ++kk) {
        const int kb = kk >> 1, e = (kk & 1) * 2;
        unsigned u0 = g32[kb][e][0],   u1 = g32[kb][e][1];
        unsigned v0 = g32[kb][e+1][0], v1 = g32[kb][e+1][1];
        asm volatile("v_permlane32_swap_b32 %0, %1" : "+v"(u0), "+v"(v0));
        asm volatile("v_permlane32_swap_b32 %0, %1" : "+v"(u1), "+v"(v1));
        union { unsigned u[4]; bfx8 bv; } fb;
        fb.u[0] = u0; fb.u[1] = u1; fb.u[2] = v0; fb.u[3] = v1;
        Pf[qb][kk] = fb.bv;
      }
    }

    // ---- O^T += V^T P : each Vf read ONCE feeds both q-blocks ----
    __builtin_amdgcn_s_setprio(1);
    #pragma unroll
    for (int kk = 0; kk < 4; ++kk)
      #pragma unroll
      for (int db = 0; db < 2; ++db) {
        const int row = db*32 + l31;
        const int c = (2*kk + l5) ^ (l31 & 7);
        const bfx8 Vf = *(const bfx8*)(Vt[cur] + row*128 + c*16);
        O[0][db] = mfma32(Vf, Pf[0][kk], O[0][db]);
        O[1][db] = mfma32(Vf, Pf[1][kk], O[1][db]);
      }
    __builtin_amdgcn_s_setprio(0);

    asm volatile("s_waitcnt vmcnt(0)" ::: "memory");   // stage(t+1) landed
    __builtin_amdgcn_s_barrier();                      // all waves done with buf cur
  }

  // ---- epilogue: finalize l (lane pair), O/l, hi/lo bf16 split ----
  #pragma unroll
  for (int qb = 0; qb < 2; ++qb) {
    const float lfull = l_[qb] + __shfl_xor(l_[qb], 32);
    const float inv = 1.f / lfull;
    const int qg = q0 + qb*32 + l31;
    #pragma unroll
    for (int db = 0; db < 2; ++db)
      #pragma unroll
      for (int rq = 0; rq < 4; ++rq) {
        bfx4 hb, lb;
        #pragma unroll
        for (int j = 0; j < 4; ++j) {
          const float v = O[qb][db][4*rq + j] * inv;
          hb[j] = (__bf16)v;
          lb[j] = (__bf16)(v - (float)hb[j]);
        }
        const size_t idx = ((size_t)(b*SEQ + qg))*CH + h*DD + db*32 + rq*8 + l5*4;
        *(bfx4*)(ao_hi + idx) = hb;
        *(bfx4*)(ao_lo + idx) = lb;
      }
  }
}

// ---------------------------------------------------------------------------
extern "C" void kernel_launch(void* const* d_in, const int* in_sizes, int n_in,
                              void* d_out, int out_size, void* d_ws, size_t ws_size,
                              hipStream_t stream) {
  const float* x         = (const float*)d_in[0];
  const float* attn_bias = (const float*)d_in[1];
  const float* qkv_w     = (const float*)d_in[2];
  const float* q_bias    = (const float*)d_in[3];
  const float* v_bias    = (const float*)d_in[4];
  const float* scale_mul = (const float*)d_in[5];
  const float* proj_w    = (const float*)d_in[6];
  const float* proj_b    = (const float*)d_in[7];
  float* out = (float*)d_out;

  char* ws = (char*)d_ws;
  size_t off = 0;
  auto alloc = [&](size_t n) { char* p = ws + off; off += (n + 255) & ~(size_t)255; return p; };
  __bf16* x_h  = (__bf16*)alloc((size_t)MROWS*CH*2);
  __bf16* w_h  = (__bf16*)alloc((size_t)3*CH*CH*2);
  __bf16* p_h  = (__bf16*)alloc((size_t)CH*CH*2);
  __bf16* p_l  = (__bf16*)alloc((size_t)CH*CH*2);
  __bf16* qkvn = (__bf16*)alloc((size_t)2*BHLD*2);   // q,k [B,H,L,D] (normalized)
  __bf16* vt   = (__bf16*)alloc((size_t)BHLD*2);     // v   [B,H,D,L]
  __bf16* ao_h = (__bf16*)alloc((size_t)MROWS*CH*2);
  __bf16* ao_l = (__bf16*)alloc((size_t)MROWS*CH*2);
  int*    flag = (int*)alloc(256);

  cast_kernel<<<MROWS*CH/4/256, 256, 0, stream>>>((const float4*)x, x_h, MROWS*CH/4);
  cast_kernel<<<3*CH*CH/4/256, 256, 0, stream>>>((const float4*)qkv_w, w_h, 3*CH*CH/4);
  split_kernel<<<CH*CH/4/256, 256, 0, stream>>>((const float4*)proj_w, p_h, p_l, CH*CH/4);

  hipMemsetAsync(flag, 0, sizeof(int), stream);
  scan_nz<<<2048, 256, 0, stream>>>((const uint4*)attn_bias, SEQ*SEQ/4, flag);

  // GEMM1 (plain bf16): [8192,3072] = x*qkv_w^T (+bias, +fused l2norm)
  gemmq<<<(MROWS/128)*(3*CH/128), 256, 0, stream>>>(
      x_h, w_h, 3*CH/128, CH, q_bias, v_bias, scale_mul, qkvn, vt);

  attn_kernel<<<NB*NH*(SEQ/256), 256, 0, stream>>>(
      qkvn, qkvn + (size_t)BHLD, vt, scale_mul, attn_bias, flag, ao_h, ao_l);

  // GEMM2 (split, fp32-accurate): d_out = attn_out * proj_w^T + proj_b
  gemm128s<<<(MROWS/128)*(CH/128), 256, 0, stream>>>(
      ao_h, ao_l, p_h, p_l, CH/128, CH, proj_b, out);
}

// Round 18
// 232.667 us; speedup vs baseline: 2.9869x; 1.1461x over previous
//
#include <hip/hip_runtime.h>
#include <cstdint>

// ---------------------------------------------------------------------------
// SelfAttention (QK-l2norm variant), MI355X/gfx950.
// R18 = R17 + gemm2 switched to PLAIN bf16 (error analysis: attn-out sigma
// ~0.025 -> plain rounding adds ~8e-4 absmax vs 3.22e-3 threshold; the
// Markidis split there was over-engineering). Attn now writes a single bf16
// output (no hi/lo pair); proj_w cast-only. Attention: R17's 32x32 reg-P
// kernel at (256,2) — NEVER >2 waves/SIMD (R6/R8/R16 spill lesson).
// ---------------------------------------------------------------------------

typedef __bf16 bfx8 __attribute__((ext_vector_type(8)));
typedef __bf16 bfx4 __attribute__((ext_vector_type(4)));
typedef float  f32x4 __attribute__((ext_vector_type(4)));
typedef float  f32x16 __attribute__((ext_vector_type(16)));

#define NB   4
#define NH   16
#define SEQ  2048
#define CH   1024
#define DD   64
#define MROWS (NB*SEQ)             /* 8192 */
#define BHLD  (NB*NH*SEQ*DD)       /* 8388608 */
#define LOG2E 1.44269504088896340736f

__device__ __forceinline__ void async16(void* lds, const void* g) {
  __builtin_amdgcn_global_load_lds((const __attribute__((address_space(1))) void*)g,
                                   (__attribute__((address_space(3))) void*)lds, 16, 0, 0);
}
__device__ __forceinline__ f32x4 mfma16(bfx8 a, bfx8 b, f32x4 c) {
  return __builtin_amdgcn_mfma_f32_16x16x32_bf16(a, b, c, 0, 0, 0);
}
__device__ __forceinline__ f32x16 mfma32(bfx8 a, bfx8 b, f32x16 c) {
  return __builtin_amdgcn_mfma_f32_32x32x16_bf16(a, b, c, 0, 0, 0);
}

extern "C" __device__ float __ocml_exp2_f32(float);
__device__ __forceinline__ float fexp2(float x) {
#if __has_builtin(__builtin_amdgcn_exp2f)
  return __builtin_amdgcn_exp2f(x);
#else
  return __ocml_exp2_f32(x);
#endif
}

// --------------------------- f32 -> bf16 cast (hi only) ---------------------
__global__ __launch_bounds__(256) void cast_kernel(const float4* __restrict__ src,
                                                   __bf16* __restrict__ dst, int n4) {
  int i = blockIdx.x * 256 + threadIdx.x;
  if (i >= n4) return;
  float4 v = src[i];
  float vv[4] = {v.x, v.y, v.z, v.w};
  bfx4 h;
  #pragma unroll
  for (int j = 0; j < 4; ++j) h[j] = (__bf16)vv[j];
  *(bfx4*)(dst + 4*(size_t)i) = h;
}

// --------------------------- bias nonzero scan ------------------------------
__global__ __launch_bounds__(256) void scan_nz(const uint4* __restrict__ p, int n4,
                                               int* __restrict__ flag) {
  unsigned acc = 0;
  const int stride = gridDim.x * 256;
  for (int i = blockIdx.x * 256 + threadIdx.x; i < n4; i += stride) {
    uint4 u = p[i];
    acc |= (u.x | u.y | u.z | u.w) & 0x7fffffffu;
  }
  if (acc) atomicOr(flag, 1);
}

// ------------------- PLAIN bf16 GEMM 128x128 (both projections) -------------
// R10-verified body. EPI==1: +concat(q_bias,0,v_bias), FUSED l2norm
// (+exp(scale)*LOG2E on q); q/k -> [B,H,L,D] bf16, v -> [B,H,D,L].
// EPI==2: +proj_b -> f32 d_out.
template<int EPI>
__global__ __launch_bounds__(256, 2) void gemmp(
    const __bf16* __restrict__ Ag, const __bf16* __restrict__ Bg,
    const int Ntiles, const int K,
    const float* __restrict__ biasA, const float* __restrict__ biasB,
    const float* __restrict__ scale_mul,
    float* __restrict__ outF, __bf16* __restrict__ outQ, __bf16* __restrict__ outV)
{
  __shared__ alignas(16) char lds[16384];   // A 8KB | B 8KB
  const int tid = threadIdx.x;
  const int lane = tid & 63, w = tid >> 6;
  const int l15 = lane & 15, l4 = lane >> 4;
  const int nwg = (int)gridDim.x;
  const int wk = (int)(blockIdx.x & 7) * (nwg >> 3) + (int)(blockIdx.x >> 3); // nwg%8==0
  const int mt = wk / Ntiles, nt = wk % Ntiles;
  const int m0 = mt * 128, n0 = nt * 128;
  const int wm = (w >> 1) * 64, wn = (w & 1) * 64;

  const f32x4 zz = {0.f, 0.f, 0.f, 0.f};
  f32x4 acc[4][4];
  #pragma unroll
  for (int a = 0; a < 4; ++a)
    #pragma unroll
    for (int b = 0; b < 4; ++b) acc[a][b] = zz;

  int st_row[2], st_c[2], st_lds[2];
  #pragma unroll
  for (int i = 0; i < 2; ++i) {
    const int s = i*256 + tid;
    st_row[i] = s >> 2;
    st_c[i]   = (s & 3) ^ ((st_row[i] >> 1) & 3);
    st_lds[i] = (i*256 + w*64) * 16;
  }

  for (int k0 = 0; k0 < K; k0 += 32) {
    __syncthreads();
    #pragma unroll
    for (int i = 0; i < 2; ++i) {
      const size_t ga = (size_t)(m0 + st_row[i]) * K + (size_t)(k0 + st_c[i]*8);
      const size_t gb = (size_t)(n0 + st_row[i]) * K + (size_t)(k0 + st_c[i]*8);
      async16(lds +        st_lds[i], Ag + ga);
      async16(lds + 8192 + st_lds[i], Bg + gb);
    }
    __syncthreads();

    bfx8 ah[4], bh[4];
    #pragma unroll
    for (int f = 0; f < 4; ++f) {
      const int ra = wm + f*16 + l15;
      ah[f] = *(const bfx8*)(lds + ra*64 + ((l4 ^ ((ra >> 1) & 3)) * 16));
      const int rb = wn + f*16 + l15;
      bh[f] = *(const bfx8*)(lds + 8192 + rb*64 + ((l4 ^ ((rb >> 1) & 3)) * 16));
    }
    __builtin_amdgcn_s_setprio(1);
    #pragma unroll
    for (int mf = 0; mf < 4; ++mf)
      #pragma unroll
      for (int nf = 0; nf < 4; ++nf)
        acc[mf][nf] = mfma16(ah[mf], bh[nf], acc[mf][nf]);
    __builtin_amdgcn_s_setprio(0);
  }

  // ---- epilogue (C/D col=l15, row=4*l4+rg) ----
  if (EPI == 1) {
    const int gcb = n0 + wn;
    const int which = gcb >> 10;                 // 0 q, 1 k, 2 v
    const int hh = (gcb & (CH-1)) >> 6;
    float smul = 1.f;
    if (which == 0) smul = __expf(fminf(scale_mul[hh], 4.605170185988091f)) * LOG2E;
    #pragma unroll
    for (int mf = 0; mf < 4; ++mf)
      #pragma unroll
      for (int rg = 0; rg < 4; ++rg) {
        #pragma unroll
        for (int nf = 0; nf < 4; ++nf) {
          const int gc = gcb + nf*16 + l15;
          acc[mf][nf][rg] += (which == 0) ? biasA[gc]
                           : ((which == 2) ? biasB[gc - 2*CH] : 0.f);
        }
        const int gr = m0 + wm + mf*16 + 4*l4 + rg;
        const int bb = gr >> 11, ll = gr & (SEQ-1);
        float sc = 1.f;
        if (which < 2) {   // fused l2norm over the 64-col head block (f32)
          float ss = 0.f;
          #pragma unroll
          for (int nf = 0; nf < 4; ++nf) ss += acc[mf][nf][rg] * acc[mf][nf][rg];
          ss += __shfl_xor(ss, 1); ss += __shfl_xor(ss, 2);
          ss += __shfl_xor(ss, 4); ss += __shfl_xor(ss, 8);
          sc = smul / fmaxf(sqrtf(ss), 1e-12f);
        }
        #pragma unroll
        for (int nf = 0; nf < 4; ++nf) {
          const float v = acc[mf][nf][rg] * sc;
          const int dd = nf*16 + l15;
          if (which < 2)
            outQ[(size_t)which*BHLD + ((size_t)((bb*NH + hh)*SEQ) + ll)*DD + dd] = (__bf16)v;
          else
            outV[((size_t)(bb*NH + hh)*DD + dd)*SEQ + ll] = (__bf16)v;
        }
      }
  } else {
    #pragma unroll
    for (int mf = 0; mf < 4; ++mf)
      #pragma unroll
      for (int nf = 0; nf < 4; ++nf)
        #pragma unroll
        for (int rg = 0; rg < 4; ++rg) {
          const int gr = m0 + wm + mf*16 + 4*l4 + rg;
          const int gc = n0 + wn + nf*16 + l15;
          outF[(size_t)gr*CH + gc] = acc[mf][nf][rg] + biasA[gc];
        }
  }
}

// --------- flash attention (bf16, 32x32, reg-P, QBLK=64/wave, sequenced) ----
// R17 body; single bf16 output (no hi/lo pair). Block = 256 q (4 waves x
// 64 q as 2 q-blocks of 32). KVBLK=64, dbuf Ks/Vt = 32KB, no P LDS.
// STq C-init = -Mh; l per-lane partial (shfl_xor(32) at end).
__global__ __launch_bounds__(256, 2) void attn_kernel(
    const __bf16* __restrict__ qn, const __bf16* __restrict__ kn,
    const __bf16* __restrict__ vtg, const float* __restrict__ scale_mul,
    const float* __restrict__ bias, const int* __restrict__ flag,
    __bf16* __restrict__ ao)
{
  __shared__ alignas(16) char Ks[2][8192];
  __shared__ alignas(16) char Vt[2][8192];

  const int tid = threadIdx.x, lane = tid & 63, w = tid >> 6;
  const int l31 = lane & 31, l5 = lane >> 5;
  const int wk = (int)(blockIdx.x & 7) * 64 + (int)(blockIdx.x >> 3);  // grid 512
  const int qt = wk & 7, h = (wk >> 3) & 15, b = wk >> 7;
  const size_t bh = ((size_t)(b*NH + h)) * SEQ * DD;
  const int hasbias = *flag;

  const float Mh = __expf(fminf(scale_mul[h], 4.605170185988091f)) * LOG2E * 1.01f;

  bfx8 Qf[2][4];
  const int q0 = qt*256 + w*64;
  #pragma unroll
  for (int qb = 0; qb < 2; ++qb)
    #pragma unroll
    for (int kd = 0; kd < 4; ++kd)
      Qf[qb][kd] = *(const bfx8*)(qn + bh + (size_t)(q0 + qb*32 + l31)*DD + kd*16 + l5*8);

  f32x16 O[2][2];
  #pragma unroll
  for (int qb = 0; qb < 2; ++qb)
    #pragma unroll
    for (int r = 0; r < 16; ++r) { O[qb][0][r] = 0.f; O[qb][1][r] = 0.f; }
  float m_[2] = {0.f, 0.f}, l_[2] = {0.f, 0.f};   // m_ in SHIFTED units (s-Mh)

  auto stage = [&](int t, int buf) {
    const __bf16* ksrc = kn + bh + (size_t)t*64*DD;
    const __bf16* vsrc = vtg + bh + (size_t)t*64;
    #pragma unroll
    for (int i = 0; i < 2; ++i) {
      const int s = i*256 + tid;
      const int row = s >> 3;
      const int c = (s & 7) ^ (row & 7);
      async16(Ks[buf] + (size_t)(i*256 + w*64)*16, ksrc + (size_t)row*DD + c*8);
      async16(Vt[buf] + (size_t)(i*256 + w*64)*16, vsrc + (size_t)row*SEQ + c*8);
    }
  };

  if (hasbias) { m_[0] = -1e30f; m_[1] = -1e30f; }

  stage(0, 0);
  asm volatile("s_waitcnt vmcnt(0)" ::: "memory");
  __builtin_amdgcn_s_barrier();

  #pragma unroll 1
  for (int t = 0; t < 32; ++t) {
    const int cur = t & 1;
    if (t + 1 < 32) stage(t + 1, cur ^ 1);   // overlaps tile-t compute

    bfx8 Pf[2][4];

    #pragma unroll
    for (int qb = 0; qb < 2; ++qb) {
      // ---- S^T - Mh = K Q^T + C(-Mh) ----
      f32x16 STq[2];
      #pragma unroll
      for (int kb = 0; kb < 2; ++kb)
        #pragma unroll
        for (int r = 0; r < 16; ++r) STq[kb][r] = -Mh;
      __builtin_amdgcn_s_setprio(1);
      #pragma unroll
      for (int kb = 0; kb < 2; ++kb)
        #pragma unroll
        for (int kd = 0; kd < 4; ++kd) {
          const int row = kb*32 + l31;
          const int c = (2*kd + l5) ^ (l31 & 7);
          const bfx8 Kf = *(const bfx8*)(Ks[cur] + row*128 + c*16);
          STq[kb] = mfma32(Kf, Qf[qb][kd], STq[kb]);
        }
      __builtin_amdgcn_s_setprio(0);

      // ---- softmax -> bf16 groups (k base = 32kb+8rh+4l5, 4 wide) ----
      unsigned g32[2][4][2];
      if (!hasbias) {
        float ls = 0.f;
        #pragma unroll
        for (int kb = 0; kb < 2; ++kb)
          #pragma unroll
          for (int rh = 0; rh < 4; ++rh) {
            bfx4 g;
            #pragma unroll
            for (int j = 0; j < 4; ++j) {
              const float e = fexp2(STq[kb][4*rh + j]);
              ls += e;
              g[j] = (__bf16)e;
            }
            union { bfx4 b; unsigned u[2]; } cv; cv.b = g;
            g32[kb][rh][0] = cv.u[0];
            g32[kb][rh][1] = cv.u[1];
          }
        l_[qb] += ls;
      } else {
        const float* bp = bias + (size_t)(q0 + qb*32 + l31)*SEQ + (size_t)t*64;
        float mx = -1e30f;
        #pragma unroll
        for (int kb = 0; kb < 2; ++kb)
          #pragma unroll
          for (int r = 0; r < 16; ++r) {
            STq[kb][r] += bp[32*kb + 4*l5 + (r & 3) + 8*(r >> 2)] * LOG2E;
            mx = fmaxf(mx, STq[kb][r]);
          }
        mx = fmaxf(mx, __shfl_xor(mx, 32));
        const bool skip = __all(mx - m_[qb] <= 12.0f) != 0;
        const float mn = skip ? m_[qb] : fmaxf(m_[qb], mx);
        float rs = 0.f;
        #pragma unroll
        for (int kb = 0; kb < 2; ++kb)
          #pragma unroll
          for (int r = 0; r < 16; ++r) {
            const float pv = fexp2(STq[kb][r] - mn);
            STq[kb][r] = pv;
            rs += pv;
          }
        if (skip) {
          l_[qb] += rs;
        } else {
          const float corr = fexp2(m_[qb] - mn);
          l_[qb] = l_[qb] * corr + rs;
          m_[qb] = mn;
          #pragma unroll
          for (int db = 0; db < 2; ++db)
            #pragma unroll
            for (int r = 0; r < 16; ++r) O[qb][db][r] *= corr;
        }
        #pragma unroll
        for (int kb = 0; kb < 2; ++kb)
          #pragma unroll
          for (int rh = 0; rh < 4; ++rh) {
            bfx4 g;
            #pragma unroll
            for (int j = 0; j < 4; ++j) g[j] = (__bf16)STq[kb][4*rh + j];
            union { bfx4 b; unsigned u[2]; } cv; cv.b = g;
            g32[kb][rh][0] = cv.u[0];
            g32[kb][rh][1] = cv.u[1];
          }
      }

      // ---- build PV B-fragments via permlane32_swap (k = 16kk+8l5+j) ----
      #pragma unroll
      for (int kk = 0; kk < 4; ++kk) {
        const int kb = kk >> 1, e = (kk & 1) * 2;
        unsigned u0 = g32[kb][e][0],   u1 = g32[kb][e][1];
        unsigned v0 = g32[kb][e+1][0], v1 = g32[kb][e+1][1];
        asm volatile("v_permlane32_swap_b32 %0, %1" : "+v"(u0), "+v"(v0));
        asm volatile("v_permlane32_swap_b32 %0, %1" : "+v"(u1), "+v"(v1));
        union { unsigned u[4]; bfx8 bv; } fb;
        fb.u[0] = u0; fb.u[1] = u1; fb.u[2] = v0; fb.u[3] = v1;
        Pf[qb][kk] = fb.bv;
      }
    }

    // ---- O^T += V^T P : each Vf read ONCE feeds both q-blocks ----
    __builtin_amdgcn_s_setprio(1);
    #pragma unroll
    for (int kk = 0; kk < 4; ++kk)
      #pragma unroll
      for (int db = 0; db < 2; ++db) {
        const int row = db*32 + l31;
        const int c = (2*kk + l5) ^ (l31 & 7);
        const bfx8 Vf = *(const bfx8*)(Vt[cur] + row*128 + c*16);
        O[0][db] = mfma32(Vf, Pf[0][kk], O[0][db]);
        O[1][db] = mfma32(Vf, Pf[1][kk], O[1][db]);
      }
    __builtin_amdgcn_s_setprio(0);

    asm volatile("s_waitcnt vmcnt(0)" ::: "memory");
    __builtin_amdgcn_s_barrier();
  }

  // ---- epilogue: finalize l (lane pair), O/l, single bf16 output ----
  #pragma unroll
  for (int qb = 0; qb < 2; ++qb) {
    const float lfull = l_[qb] + __shfl_xor(l_[qb], 32);
    const float inv = 1.f / lfull;
    const int qg = q0 + qb*32 + l31;
    #pragma unroll
    for (int db = 0; db < 2; ++db)
      #pragma unroll
      for (int rq = 0; rq < 4; ++rq) {
        bfx4 hb;
        #pragma unroll
        for (int j = 0; j < 4; ++j)
          hb[j] = (__bf16)(O[qb][db][4*rq + j] * inv);
        const size_t idx = ((size_t)(b*SEQ + qg))*CH + h*DD + db*32 + rq*8 + l5*4;
        *(bfx4*)(ao + idx) = hb;
      }
  }
}

// ---------------------------------------------------------------------------
extern "C" void kernel_launch(void* const* d_in, const int* in_sizes, int n_in,
                              void* d_out, int out_size, void* d_ws, size_t ws_size,
                              hipStream_t stream) {
  const float* x         = (const float*)d_in[0];
  const float* attn_bias = (const float*)d_in[1];
  const float* qkv_w     = (const float*)d_in[2];
  const float* q_bias    = (const float*)d_in[3];
  const float* v_bias    = (const float*)d_in[4];
  const float* scale_mul = (const float*)d_in[5];
  const float* proj_w    = (const float*)d_in[6];
  const float* proj_b    = (const float*)d_in[7];
  float* out = (float*)d_out;

  char* ws = (char*)d_ws;
  size_t off = 0;
  auto alloc = [&](size_t n) { char* p = ws + off; off += (n + 255) & ~(size_t)255; return p; };
  __bf16* x_h  = (__bf16*)alloc((size_t)MROWS*CH*2);
  __bf16* w_h  = (__bf16*)alloc((size_t)3*CH*CH*2);
  __bf16* p_h  = (__bf16*)alloc((size_t)CH*CH*2);
  __bf16* qkvn = (__bf16*)alloc((size_t)2*BHLD*2);   // q,k [B,H,L,D] (normalized)
  __bf16* vt   = (__bf16*)alloc((size_t)BHLD*2);     // v   [B,H,D,L]
  __bf16* ao   = (__bf16*)alloc((size_t)MROWS*CH*2); // attn out bf16
  int*    flag = (int*)alloc(256);

  cast_kernel<<<MROWS*CH/4/256, 256, 0, stream>>>((const float4*)x, x_h, MROWS*CH/4);
  cast_kernel<<<3*CH*CH/4/256, 256, 0, stream>>>((const float4*)qkv_w, w_h, 3*CH*CH/4);
  cast_kernel<<<CH*CH/4/256, 256, 0, stream>>>((const float4*)proj_w, p_h, CH*CH/4);

  hipMemsetAsync(flag, 0, sizeof(int), stream);
  scan_nz<<<2048, 256, 0, stream>>>((const uint4*)attn_bias, SEQ*SEQ/4, flag);

  // GEMM1 (plain bf16): [8192,3072] = x*qkv_w^T (+bias, +fused l2norm)
  gemmp<1><<<(MROWS/128)*(3*CH/128), 256, 0, stream>>>(
      x_h, w_h, 3*CH/128, CH, q_bias, v_bias, scale_mul, nullptr, qkvn, vt);

  attn_kernel<<<NB*NH*(SEQ/256), 256, 0, stream>>>(
      qkvn, qkvn + (size_t)BHLD, vt, scale_mul, attn_bias, flag, ao);

  // GEMM2 (plain bf16): d_out = attn_out * proj_w^T + proj_b
  gemmp<2><<<(MROWS/128)*(CH/128), 256, 0, stream>>>(
      ao, p_h, CH/128, CH, proj_b, nullptr, nullptr, out, nullptr, nullptr);
}